// Round 2
// baseline (137.901 us; speedup 1.0000x reference)
//
#include <hip/hip_runtime.h>

// Embedding lookup: out[row, :] = weight[ids[row], :]
// ids: 4*2048 = 8192 int32, weight: 32000 x 768 fp32, out: 8192 x 768 fp32.
//
// v2b: latency-hiding rewrite (v2 + compile fix: native clang vector type for
// __builtin_nontemporal_store, which rejects HIP_vector_type<float,4>).
//   - 4 rows per block, 256 threads, 3 float4 per thread (fully unrolled -> 3
//     independent id loads, 3 independent gathers, 3 stores in flight).
//   - grid = 2048 blocks = 8 blocks/CU x 4 waves = 32 waves/CU (max occupancy).
//   - nontemporal stores: output is never re-read; keeps the 98 MB weight table
//     resident in the 256 MB Infinity Cache across iterations.

typedef float f4 __attribute__((ext_vector_type(4)));

#define DIM 768
#define DIM_VEC (DIM / 4)              // 192 float4 per row
#define RPB 4                          // rows per block
#define THREADS 256
#define F4_PER_BLOCK (RPB * DIM_VEC)   // 768
#define ITERS (F4_PER_BLOCK / THREADS) // 3

__global__ __launch_bounds__(THREADS) void embed_gather_kernel(
    const int* __restrict__ ids,
    const f4* __restrict__ weight,
    f4* __restrict__ out) {
    const int tid = threadIdx.x;
    const int row0 = blockIdx.x * RPB;

    int r[ITERS], c[ITERS], id[ITERS];
#pragma unroll
    for (int i = 0; i < ITERS; ++i) {
        const int flat = tid + i * THREADS;     // 0..767
        r[i] = flat / DIM_VEC;                  // const divisor -> mul/shift
        c[i] = flat - r[i] * DIM_VEC;
        id[i] = ids[row0 + r[i]];               // mostly wave-uniform -> broadcast
    }

    f4 v[ITERS];
#pragma unroll
    for (int i = 0; i < ITERS; ++i)
        v[i] = weight[(size_t)id[i] * DIM_VEC + c[i]];

#pragma unroll
    for (int i = 0; i < ITERS; ++i)
        __builtin_nontemporal_store(
            v[i], &out[(size_t)(row0 + r[i]) * DIM_VEC + c[i]]);
}

extern "C" void kernel_launch(void* const* d_in, const int* in_sizes, int n_in,
                              void* d_out, int out_size, void* d_ws, size_t ws_size,
                              hipStream_t stream) {
    const int* ids = (const int*)d_in[0];        // 8192 int32
    const f4* weight = (const f4*)d_in[1];       // 32000*192 float4
    f4* out = (f4*)d_out;                        // 8192*192 float4

    const int n_rows = in_sizes[0];              // 8192 (divisible by RPB)
    embed_gather_kernel<<<n_rows / RPB, THREADS, 0, stream>>>(ids, weight, out);
}

// Round 3
// 137.322 us; speedup vs baseline: 1.0042x; 1.0042x over previous
//
#include <hip/hip_runtime.h>

// Embedding lookup: out[row, :] = weight[ids[row], :]
// ids: 4*2048 = 8192 int32, weight: 32000 x 768 fp32, out: 8192 x 768 fp32.
//
// v3: v2b minus nontemporal stores.
// Rationale: NT stores stream 24 MB directly to HBM at HBM write latency/BW;
// normal stores retire into L2/L3 (24 MB << 256 MB L3) and write back lazily.
// The NT hint bought nothing for weight-table residency (the harness's own
// 393 MB poison fills dominate L3 traffic either way) and costs store
// throughput. Structure otherwise unchanged:
//   - 4 rows/block, 256 threads, 3 float4/thread fully unrolled
//     (3 independent gathers in flight per thread).
//   - grid = 2048 blocks = 8 blocks/CU x 4 waves = 32 waves/CU (max occupancy).

typedef float f4 __attribute__((ext_vector_type(4)));

#define DIM 768
#define DIM_VEC (DIM / 4)              // 192 float4 per row
#define RPB 4                          // rows per block
#define THREADS 256
#define F4_PER_BLOCK (RPB * DIM_VEC)   // 768
#define ITERS (F4_PER_BLOCK / THREADS) // 3

__global__ __launch_bounds__(THREADS) void embed_gather_kernel(
    const int* __restrict__ ids,
    const f4* __restrict__ weight,
    f4* __restrict__ out) {
    const int tid = threadIdx.x;
    const int row0 = blockIdx.x * RPB;

    int r[ITERS], c[ITERS], id[ITERS];
#pragma unroll
    for (int i = 0; i < ITERS; ++i) {
        const int flat = tid + i * THREADS;     // 0..767
        r[i] = flat / DIM_VEC;                  // const divisor -> mul/shift
        c[i] = flat - r[i] * DIM_VEC;
        id[i] = ids[row0 + r[i]];               // cached after first touch
    }

    f4 v[ITERS];
#pragma unroll
    for (int i = 0; i < ITERS; ++i)
        v[i] = weight[(size_t)id[i] * DIM_VEC + c[i]];

#pragma unroll
    for (int i = 0; i < ITERS; ++i)
        out[(size_t)(row0 + r[i]) * DIM_VEC + c[i]] = v[i];
}

extern "C" void kernel_launch(void* const* d_in, const int* in_sizes, int n_in,
                              void* d_out, int out_size, void* d_ws, size_t ws_size,
                              hipStream_t stream) {
    const int* ids = (const int*)d_in[0];        // 8192 int32
    const f4* weight = (const f4*)d_in[1];       // 32000*192 float4
    f4* out = (f4*)d_out;                        // 8192*192 float4

    const int n_rows = in_sizes[0];              // 8192 (divisible by RPB)
    embed_gather_kernel<<<n_rows / RPB, THREADS, 0, stream>>>(ids, weight, out);
}